// Round 8
// baseline (432.246 us; speedup 1.0000x reference)
//
#include <hip/hip_runtime.h>
#include <hip/hip_bf16.h>
#include <stdint.h>

typedef __bf16 bf16x8_t __attribute__((ext_vector_type(8)));
typedef short  s16x8_t  __attribute__((ext_vector_type(8)));
typedef unsigned short u16x4_t __attribute__((ext_vector_type(4)));
typedef float  f32x4_t __attribute__((ext_vector_type(4)));

#define NTOK 3072
#define NHEAD 8
#define NSPLIT 4           // flash KV splits (96 tiles / 4 = 24 each)

__device__ __forceinline__ unsigned short f2bf(float f) {
  union { float f; uint32_t u; } v; v.f = f;
  uint32_t r = v.u + 0x7fffu + ((v.u >> 16) & 1u);
  return (unsigned short)(r >> 16);
}
__device__ __forceinline__ float bf2f(unsigned short s) {
  union { uint32_t u; float f; } v; v.u = ((uint32_t)s) << 16;
  return v.f;
}

__device__ __forceinline__ void gload_lds16(const void* g, void* lds) {
  __builtin_amdgcn_global_load_lds(
      (const __attribute__((address_space(1))) uint32_t*)g,
      (__attribute__((address_space(3))) uint32_t*)lds, 16, 0, 0);
}

// DPP lane-shuffle within 16-lane rows (compile-time ctrl)
template <int CTRL>
__device__ __forceinline__ float dpp_mv(float x) {
  union { float f; int i; } u; u.f = x;
  u.i = __builtin_amdgcn_update_dpp(0, u.i, CTRL, 0xf, 0xf, true);
  return u.f;
}
// reduce across each contiguous 16-lane group (no LDS/ds ops)
__device__ __forceinline__ float red_max16(float x) {
  x = fmaxf(x, dpp_mv<0xB1>(x));   // quad_perm xor1
  x = fmaxf(x, dpp_mv<0x4E>(x));   // quad_perm xor2
  x = fmaxf(x, dpp_mv<0x141>(x));  // row_half_mirror (quad 0<->1)
  x = fmaxf(x, dpp_mv<0x140>(x));  // row_mirror (half 0<->1)
  return x;
}
__device__ __forceinline__ float red_sum16(float x) {
  x += dpp_mv<0xB1>(x);
  x += dpp_mv<0x4E>(x);
  x += dpp_mv<0x141>(x);
  x += dpp_mv<0x140>(x);
  return x;
}

// ---------------- merged prep kernel: 5 transposes + x copy, job-table ----------
// jobs: [0,384) qkvw, [384,512) law, [512,544) lw, [544,560) f1, [560,576) f2,
//       [576,624) x-copy (64 rows each)
__global__ void prep_all(const float* __restrict__ WQ, const float* __restrict__ WK,
                         const float* __restrict__ WV, const float* __restrict__ law,
                         const float* __restrict__ lw, const float* __restrict__ f1w,
                         const float* __restrict__ f2w, const float* __restrict__ x,
                         unsigned short* __restrict__ qkvwT, unsigned short* __restrict__ lawT,
                         unsigned short* __restrict__ lwT, unsigned short* __restrict__ f1T,
                         unsigned short* __restrict__ f2T, unsigned short* __restrict__ xa) {
  __shared__ float tile[64][65];
  const int id = blockIdx.x;
  const int t = threadIdx.x;
  if (id >= 576) {  // x copy: 64 rows x 256 cols, xa row stride 512
    int n0 = (id - 576) * 64;
    int col = (t & 63) * 4;
#pragma unroll
    for (int i = 0; i < 16; ++i) {
      int n = n0 + i * 4 + (t >> 6);
      f32x4_t v = *(const f32x4_t*)(x + (size_t)n * 256 + col);
      u16x4_t o;
#pragma unroll
      for (int j = 0; j < 4; ++j) o[j] = f2bf(v[j]);
      *(u16x4_t*)(xa + (size_t)n * 512 + col) = o;
    }
    return;
  }
  const float* src; unsigned short* dst; int sld, dld, d0, e0;
  if (id < 384) {
    int z = id >> 4, tl = id & 15;
    int op = z >> 3, hh = z & 7;
    src = ((op == 0) ? WQ : (op == 1) ? WK : WV) + (size_t)hh * 65536;
    dst = qkvwT + (size_t)z * 65536;
    sld = 256; dld = 256; d0 = (tl >> 2) * 64; e0 = (tl & 3) * 64;
  } else if (id < 512) {
    int tl = id - 384;
    src = law; dst = lawT; sld = 256; dld = 2048;
    d0 = (tl >> 2) * 64; e0 = (tl & 3) * 64;
  } else if (id < 544) {
    int tl = id - 512;
    src = lw; dst = lwT; sld = 256; dld = 512;
    d0 = (tl >> 2) * 64; e0 = (tl & 3) * 64;
  } else if (id < 560) {
    int tl = id - 544;
    src = f1w; dst = f1T; sld = 256; dld = 256;
    d0 = (tl >> 2) * 64; e0 = (tl & 3) * 64;
  } else {
    int tl = id - 560;
    src = f2w; dst = f2T; sld = 256; dld = 256;
    d0 = (tl >> 2) * 64; e0 = (tl & 3) * 64;
  }
  int tr = t >> 4, tc4 = (t & 15) * 4;
#pragma unroll
  for (int i = 0; i < 4; ++i) {
    int d = i * 16 + tr;
    f32x4_t v = *(const f32x4_t*)(src + (size_t)(d0 + d) * sld + e0 + tc4);
    tile[d][tc4] = v[0]; tile[d][tc4 + 1] = v[1]; tile[d][tc4 + 2] = v[2]; tile[d][tc4 + 3] = v[3];
  }
  __syncthreads();
#pragma unroll
  for (int i = 0; i < 4; ++i) {
    int e = i * 16 + tr;
    u16x4_t o;
#pragma unroll
    for (int j = 0; j < 4; ++j) o[j] = f2bf(tile[tc4 + j][e]);
    *(u16x4_t*)(dst + (size_t)(e0 + e) * dld + d0 + tc4) = o;
  }
}

// ---------------- generic MFMA GEMM (templated tile, swizzled LDS) --------
// C[M x N] = A[M x K] (bf16, lda) @ Bt[N x K]^T (bf16, ldb); K-range = blockIdx.z*Klen ..
// flags: 1 = relu, 2 = bf16 out, 4 = (acc+bias)*rsqrt(deg[row]), 8 = f32 partial out
template <int BM, int BN>
__global__ __launch_bounds__(256, 2) void gemm_kernel(
    const unsigned short* __restrict__ A, int lda,
    const unsigned short* __restrict__ B, int ldb,
    void* __restrict__ Cout, int ldc, int Klen,
    const float* __restrict__ bias,
    const float* __restrict__ resid, int ldr,
    const float* __restrict__ deg, int flags,
    float* __restrict__ part, long pstride) {
  constexpr int WM = BM / 2, WN = BN / 2, FM = WM / 16, FN = WN / 16;
  __shared__ unsigned short As[BM * 32];
  __shared__ unsigned short Bs[BN * 32];
  const int t = threadIdx.x;
  const int w = t >> 6, l = t & 63;
  const int l15 = l & 15, lhi = l >> 4;
  const int row0 = blockIdx.y * BM, col0 = blockIdx.x * BN;
  const int wr = (w >> 1) * WM, wc = (w & 1) * WN;

  f32x4_t acc[FM][FN];
#pragma unroll
  for (int m = 0; m < FM; ++m)
#pragma unroll
    for (int n = 0; n < FN; ++n) acc[m][n] = (f32x4_t){0.f, 0.f, 0.f, 0.f};

  const int srow = l >> 2;          // row within 16-row chunk
  const int spc  = (l & 3) * 16;    // physical col byte
  const int kofs0 = blockIdx.z * Klen;
  const int nkt = Klen >> 5;
  for (int kt = 0; kt < nkt; ++kt) {
    const int koff = kofs0 + kt * 32;
    __syncthreads();
#pragma unroll
    for (int c = w; c < BM / 16; c += 4) {
      int ar = c * 16 + srow;
      int lcb = spc ^ (((ar >> 1) & 3) << 4);
      gload_lds16(A + (size_t)(row0 + ar) * lda + koff + (lcb >> 1), &As[c * 512]);
    }
#pragma unroll
    for (int c = w; c < BN / 16; c += 4) {
      int br = c * 16 + srow;
      int lcb = spc ^ (((br >> 1) & 3) << 4);
      gload_lds16(B + (size_t)(col0 + br) * ldb + koff + (lcb >> 1), &Bs[c * 512]);
    }
    __syncthreads();
    bf16x8_t af[FM], bfr[FN];
#pragma unroll
    for (int m = 0; m < FM; ++m) {
      int ar = wr + m * 16 + l15;
      af[m] = *(const bf16x8_t*)(&As[(ar * 64 + ((lhi * 16) ^ (((ar >> 1) & 3) << 4))) >> 1]);
    }
#pragma unroll
    for (int n = 0; n < FN; ++n) {
      int br = wc + n * 16 + l15;
      bfr[n] = *(const bf16x8_t*)(&Bs[(br * 64 + ((lhi * 16) ^ (((br >> 1) & 3) << 4))) >> 1]);
    }
#pragma unroll
    for (int m = 0; m < FM; ++m)
#pragma unroll
      for (int n = 0; n < FN; ++n)
        acc[m][n] = __builtin_amdgcn_mfma_f32_16x16x32_bf16(af[m], bfr[n], acc[m][n], 0, 0, 0);
  }

  const bool relu = flags & 1, obf = flags & 2, dsc = flags & 4, ppart = flags & 8;
#pragma unroll
  for (int m = 0; m < FM; ++m) {
#pragma unroll
    for (int r = 0; r < 4; ++r) {
      int grow = row0 + wr + m * 16 + lhi * 4 + r;
      float sc = dsc ? rsqrtf(deg[grow]) : 1.0f;
#pragma unroll
      for (int n = 0; n < FN; ++n) {
        int gcol = col0 + wc + n * 16 + l15;
        float v = acc[m][n][r];
        if (ppart) {
          part[(size_t)blockIdx.z * pstride + (size_t)grow * ldc + gcol] = v;
          continue;
        }
        if (bias) v += bias[gcol];
        v *= sc;
        if (resid) v += resid[(size_t)grow * ldr + gcol];
        if (relu) v = fmaxf(v, 0.f);
        if (obf)
          ((unsigned short*)Cout)[(size_t)grow * ldc + gcol] = f2bf(v);
        else
          ((float*)Cout)[(size_t)grow * ldc + gcol] = v;
      }
    }
  }
}

// reduce attn split-K partials: xa[n][256+d] = bf16((sum_z part + lab[d]) * rsqrt(deg[n]))
__global__ void attn_reduce(const float* __restrict__ part, const float* __restrict__ lab,
                            const float* __restrict__ deg, unsigned short* __restrict__ xa) {
  int n = blockIdx.x, d = threadIdx.x;
  float s = 0.f;
#pragma unroll
  for (int z = 0; z < 4; ++z) s += part[((size_t)z * NTOK + n) * 256 + d];
  xa[(size_t)n * 512 + 256 + d] = f2bf((s + lab[d]) * rsqrtf(deg[n]));
}

// ---------------- flash attention (split-KV, async-staged single-buffer) ----
// qkv: (N x 6144) bf16 = [Q heads | K heads | V heads]
// pO: [NSPLIT][H][N][256] bf16 unnormalized partials; ml: [NSPLIT][H][N][2] f32 (m,l)
// Loop: QK^T -> barrier A -> issue K/V(t+1) -> softmax+PV (hides K/V latency)
//       -> barrier B (drains K) -> pack V(t+1). 3 blocks/CU (launch_bounds 3).
#define VSW(e) ((((((e) >> 1) & 3) ^ (((e) >> 3) & 3))) << 4)
__global__ __launch_bounds__(256, 3) void flash_kernel(
    const unsigned short* __restrict__ qkv, unsigned short* __restrict__ pO,
    float* __restrict__ ml) {
  __shared__ unsigned short Ks[32 * 256];   // swizzled: byte ^= (row&7)<<4
  __shared__ unsigned short Vt[256 * 32];   // transposed, swizzled: byte ^= VSW(e)
  __shared__ unsigned short Ps[4][16 * 32]; // per-wave P, byte ^= ((row>>1)&3)<<4
  const int bid = blockIdx.x;
  const int hs = bid % (NHEAD * NSPLIT);
  const int qb = bid / (NHEAD * NSPLIT);
  const int h = hs / NSPLIT;
  const int split = hs % NSPLIT;
  const int q0 = qb * 64;
  const int t = threadIdx.x, w = t >> 6, l = t & 63;
  const int l15 = l & 15, lhi = l >> 4;

  const int vn0 = (t & 7) * 4;        // V-staging: 4 kv rows
  const int ve0 = (t >> 3) * 8;       // 8 features

  auto issueV = [&](int kv0, s16x8_t rv[4]) {
    const unsigned short* Vg = qkv + (size_t)(kv0 + vn0) * 6144 + 4096 + h * 256 + ve0;
#pragma unroll
    for (int rr = 0; rr < 4; ++rr) rv[rr] = *(const s16x8_t*)(Vg + rr * 6144);
  };
  auto issueK = [&](int kv0) {
    int rh = l >> 5;
    int pc = (l & 31) * 16;
#pragma unroll
    for (int i = 0; i < 4; ++i) {
      int c = w * 4 + i;
      int kr = c * 2 + rh;
      int lcb = pc ^ ((kr & 7) << 4);
      gload_lds16(qkv + (size_t)(kv0 + kr) * 6144 + 2048 + h * 256 + (lcb >> 1),
                  &Ks[c * 512]);
    }
  };
  auto packV = [&](s16x8_t rv[4]) {
#pragma unroll
    for (int j = 0; j < 8; ++j) {
      int e = ve0 + j;
      uint64_t pk = (uint64_t)(unsigned short)rv[0][j] |
                    ((uint64_t)(unsigned short)rv[1][j] << 16) |
                    ((uint64_t)(unsigned short)rv[2][j] << 32) |
                    ((uint64_t)(unsigned short)rv[3][j] << 48);
      int pb = e * 64 + ((vn0 * 2) ^ VSW(e));
      *(uint64_t*)(&Vt[pb >> 1]) = pk;
    }
  };

  // Q fragments (held in registers for the whole loop)
  bf16x8_t qf[8];
  {
    const unsigned short* Qb = qkv + (size_t)(q0 + w * 16 + l15) * 6144 + h * 256 + lhi * 8;
#pragma unroll
    for (int kk = 0; kk < 8; ++kk) qf[kk] = *(const bf16x8_t*)(Qb + kk * 32);
  }
  f32x4_t o[16];
#pragma unroll
  for (int et = 0; et < 16; ++et) o[et] = (f32x4_t){0.f, 0.f, 0.f, 0.f};
  float m_run[4] = {-1e30f, -1e30f, -1e30f, -1e30f};
  float l_run[4] = {0.f, 0.f, 0.f, 0.f};

  const int nt0 = split * (96 / NSPLIT), nt1 = nt0 + 96 / NSPLIT;

  // prologue: stage tile nt0
  {
    s16x8_t rva[4];
    issueV(nt0 * 32, rva);
    issueK(nt0 * 32);
    packV(rva);               // waits V regs; K loads drained by barrier below
  }
  __syncthreads();

  for (int nt = nt0; nt < nt1; ++nt) {
    const int kv0 = nt * 32;
    const bool have_nxt = (nt + 1 < nt1);

    // S = Q Kt : 16x32 per wave
    f32x4_t s[2];
#pragma unroll
    for (int ni = 0; ni < 2; ++ni) s[ni] = (f32x4_t){0.f, 0.f, 0.f, 0.f};
    __builtin_amdgcn_s_setprio(1);
#pragma unroll
    for (int kk = 0; kk < 8; ++kk) {
#pragma unroll
      for (int ni = 0; ni < 2; ++ni) {
        int br = ni * 16 + l15;
        bf16x8_t kb = *(const bf16x8_t*)(&Ks[(br * 512 + ((kk * 64 + lhi * 16) ^ ((br & 7) << 4))) >> 1]);
        s[ni] = __builtin_amdgcn_mfma_f32_16x16x32_bf16(qf[kk], kb, s[ni], 0, 0, 0);
      }
    }
    __builtin_amdgcn_s_setprio(0);
    __syncthreads();                 // A: all waves done reading Ks

    s16x8_t rvb[4];
    if (have_nxt) {
      issueV(kv0 + 32, rvb);         // in flight until packV (after barrier B)
      issueK(kv0 + 32);              // in flight until barrier B
    }

    // online softmax (DPP 16-lane reduces, no ds ops)
    float p[2][4];
    float alpha[4];
#pragma unroll
    for (int r = 0; r < 4; ++r) {
      int grow = q0 + w * 16 + lhi * 4 + r;
      float sv0 = s[0][r] * 0.0625f;
      float sv1 = s[1][r] * 0.0625f;
      if (kv0 + l15 == grow) sv0 = -1e30f;
      if (kv0 + 16 + l15 == grow) sv1 = -1e30f;
      float mx = red_max16(fmaxf(sv0, sv1));
      float mn = fmaxf(m_run[r], mx);
      alpha[r] = __expf(m_run[r] - mn);
      m_run[r] = mn;
      float pv0 = __expf(sv0 - mn);
      float pv1 = __expf(sv1 - mn);
      p[0][r] = pv0; p[1][r] = pv1;
      float ls = red_sum16(pv0 + pv1);
      l_run[r] = l_run[r] * alpha[r] + ls;
    }
#pragma unroll
    for (int et = 0; et < 16; ++et)
#pragma unroll
      for (int r = 0; r < 4; ++r) o[et][r] *= alpha[r];

    // P -> per-wave LDS (bf16), then PV from Vt
    unsigned short* Pw = &Ps[w][0];
#pragma unroll
    for (int ni = 0; ni < 2; ++ni)
#pragma unroll
      for (int r = 0; r < 4; ++r) {
        int prow = lhi * 4 + r;
        int pb = prow * 64 + ((((ni * 16 + l15) * 2)) ^ (((prow >> 1) & 3) << 4));
        Pw[pb >> 1] = f2bf(p[ni][r]);
      }
    bf16x8_t pa = *(const bf16x8_t*)(&Pw[(l15 * 64 + ((lhi * 16) ^ (((l15 >> 1) & 3) << 4))) >> 1]);
    __builtin_amdgcn_s_setprio(1);
#pragma unroll
    for (int et = 0; et < 16; ++et) {
      int er = et * 16 + l15;
      bf16x8_t vb = *(const bf16x8_t*)(&Vt[(er * 64 + ((lhi * 16) ^ VSW(er))) >> 1]);
      o[et] = __builtin_amdgcn_mfma_f32_16x16x32_bf16(pa, vb, o[et], 0, 0, 0);
    }
    __builtin_amdgcn_s_setprio(0);

    if (have_nxt) {
      __syncthreads();               // B: drains K(t+1); Vt free (all PV done)
      packV(rvb);                    // Vt(t+1); visible to others by barrier A(t+1)
    }
  }

  // write unnormalized partial O + (m,l)
  const size_t sh = (size_t)(split * NHEAD + h);
#pragma unroll
  for (int et = 0; et < 16; ++et)
#pragma unroll
    for (int r = 0; r < 4; ++r) {
      int grow = q0 + w * 16 + lhi * 4 + r;
      pO[(sh * NTOK + grow) * 256 + et * 16 + l15] = f2bf(o[et][r]);
    }
  if (l15 == 0) {
#pragma unroll
    for (int r = 0; r < 4; ++r) {
      int grow = q0 + w * 16 + lhi * 4 + r;
      ml[(sh * NTOK + grow) * 2] = m_run[r];
      ml[(sh * NTOK + grow) * 2 + 1] = l_run[r];
    }
  }
}

// combine splits: acat[n][h*256+e] = sum_s w_s O_s / sum_s w_s l_s
__global__ void flash_combine(const unsigned short* __restrict__ pO,
                              const float* __restrict__ ml,
                              unsigned short* __restrict__ acat) {
  int n = blockIdx.x, t = threadIdx.x;
  int h = t >> 5, e0 = (t & 31) * 8;
  float ms[NSPLIT], ls[NSPLIT];
  float M = -1e30f;
#pragma unroll
  for (int s = 0; s < NSPLIT; ++s) {
    size_t b = ((size_t)(s * NHEAD + h) * NTOK + n) * 2;
    ms[s] = ml[b]; ls[s] = ml[b + 1];
    M = fmaxf(M, ms[s]);
  }
  float den = 0.f;
  float num[8];
#pragma unroll
  for (int j = 0; j < 8; ++j) num[j] = 0.f;
#pragma unroll
  for (int s = 0; s < NSPLIT; ++s) {
    float ws = __expf(ms[s] - M);
    den += ws * ls[s];
    s16x8_t ov = *(const s16x8_t*)(pO + ((size_t)(s * NHEAD + h) * NTOK + n) * 256 + e0);
#pragma unroll
    for (int j = 0; j < 8; ++j) num[j] += ws * bf2f((unsigned short)ov[j]);
  }
  float rden = 1.0f / den;
  s16x8_t out;
#pragma unroll
  for (int j = 0; j < 8; ++j) out[j] = (short)f2bf(num[j] * rden);
  *(s16x8_t*)(acat + (size_t)n * 2048 + h * 256 + e0) = out;
}

// ---------------- LayerNorm: 1 wave per row, 4 rows per block ----------------
__global__ void ln_kernel(const float* __restrict__ u, const float* __restrict__ g,
                          const float* __restrict__ b, float* __restrict__ outf,
                          unsigned short* __restrict__ outb) {
  int row = blockIdx.x * 4 + (threadIdx.x >> 6);
  int l = threadIdx.x & 63;
  const float* ur = u + (size_t)row * 256;
  f32x4_t v = *(const f32x4_t*)(ur + l * 4);
  float s = v[0] + v[1] + v[2] + v[3];
#pragma unroll
  for (int m = 1; m < 64; m <<= 1) s += __shfl_xor(s, m);
  float mu = s * (1.0f / 256.0f);
  f32x4_t d;
  float vs = 0.f;
#pragma unroll
  for (int i = 0; i < 4; ++i) { d[i] = v[i] - mu; vs += d[i] * d[i]; }
#pragma unroll
  for (int m = 1; m < 64; m <<= 1) vs += __shfl_xor(vs, m);
  float rstd = rsqrtf(vs * (1.0f / 256.0f) + 1e-5f);
  f32x4_t gg = *(const f32x4_t*)(g + l * 4);
  f32x4_t bb = *(const f32x4_t*)(b + l * 4);
#pragma unroll
  for (int i = 0; i < 4; ++i) {
    float o = d[i] * rstd * gg[i] + bb[i];
    if (outf) outf[(size_t)row * 256 + l * 4 + i] = o;
    if (outb) outb[(size_t)row * 256 + l * 4 + i] = f2bf(o);
  }
}

// ---------------- launcher ----------------
extern "C" void kernel_launch(void* const* d_in, const int* in_sizes, int n_in,
                              void* d_out, int out_size, void* d_ws, size_t ws_size,
                              hipStream_t stream) {
  const float* x    = (const float*)d_in[0];
  const float* deg  = (const float*)d_in[1];
  const float* WQ   = (const float*)d_in[2];
  const float* WK   = (const float*)d_in[3];
  const float* WV   = (const float*)d_in[4];
  const float* law  = (const float*)d_in[5];
  const float* lab  = (const float*)d_in[6];
  const float* lw   = (const float*)d_in[7];
  const float* lb   = (const float*)d_in[8];
  const float* ln1g = (const float*)d_in[9];
  const float* ln1b = (const float*)d_in[10];
  const float* f1w  = (const float*)d_in[11];
  const float* f1b  = (const float*)d_in[12];
  const float* f2w  = (const float*)d_in[13];
  const float* f2b  = (const float*)d_in[14];
  const float* ln2g = (const float*)d_in[15];
  const float* ln2b = (const float*)d_in[16];

  char* ws = (char*)d_ws;
  size_t off = 0;
  auto alloc = [&](size_t bytes) {
    void* p = ws + off;
    off += (bytes + 255) & ~(size_t)255;
    return p;
  };
  unsigned short* qkvwT = (unsigned short*)alloc((size_t)6144 * 256 * 2);
  unsigned short* lawT  = (unsigned short*)alloc((size_t)256 * 2048 * 2);
  unsigned short* lwT   = (unsigned short*)alloc((size_t)256 * 512 * 2);
  unsigned short* f1T   = (unsigned short*)alloc((size_t)256 * 256 * 2);
  unsigned short* f2T   = (unsigned short*)alloc((size_t)256 * 256 * 2);
  unsigned short* xa    = (unsigned short*)alloc((size_t)NTOK * 512 * 2);
  unsigned short* qkv   = (unsigned short*)alloc((size_t)NTOK * 6144 * 2);
  unsigned short* acat  = (unsigned short*)alloc((size_t)NTOK * 2048 * 2);
  unsigned short* pO    = (unsigned short*)alloc((size_t)NSPLIT * NHEAD * NTOK * 256 * 2);
  float*          mlp   = (float*)alloc((size_t)NSPLIT * NHEAD * NTOK * 2 * 4);
  float*          apart = (float*)alloc((size_t)4 * NTOK * 256 * 4);
  float*          u1    = (float*)alloc((size_t)NTOK * 256 * 4);
  float*          x1f   = (float*)alloc((size_t)NTOK * 256 * 4);
  unsigned short* x1b   = (unsigned short*)alloc((size_t)NTOK * 256 * 2);
  unsigned short* tb    = (unsigned short*)alloc((size_t)NTOK * 256 * 2);
  float*          u2    = (float*)alloc((size_t)NTOK * 256 * 4);

  prep_all<<<624, 256, 0, stream>>>(WQ, WK, WV, law, lw, f1w, f2w, x,
                                    qkvwT, lawT, lwT, f1T, f2T, xa);

  // QKV: (3072x256)@(256x6144) -> qkv bf16
  gemm_kernel<128, 128><<<dim3(48, 24), 256, 0, stream>>>(
      xa, 512, qkvwT, 256, qkv, 6144, 256, nullptr, nullptr, 0, nullptr, 2, nullptr, 0);

  flash_kernel<<<NTOK / 64 * NHEAD * NSPLIT, 256, 0, stream>>>(qkv, pO, mlp);
  flash_combine<<<NTOK, 256, 0, stream>>>(pO, mlp, acat);

  // attn_out split-K x4 -> f32 partials, then reduce (+bias)*rsqrt(deg) -> xa[:,256:512]
  gemm_kernel<64, 64><<<dim3(4, 48, 4), 256, 0, stream>>>(
      acat, 2048, lawT, 2048, nullptr, 256, 512, nullptr, nullptr, 0, nullptr, 8,
      apart, (long)NTOK * 256);
  attn_reduce<<<NTOK, 256, 0, stream>>>(apart, lab, deg, xa);

  // u1 = [x|a2] @ lin_w + lin_b + x
  gemm_kernel<64, 64><<<dim3(4, 48), 256, 0, stream>>>(
      xa, 512, lwT, 512, u1, 256, 512, lb, x, 256, nullptr, 0, nullptr, 0);
  ln_kernel<<<NTOK / 4, 256, 0, stream>>>(u1, ln1g, ln1b, x1f, x1b);

  // tb = relu(x1 @ fnn1 + b1)
  gemm_kernel<64, 64><<<dim3(4, 48), 256, 0, stream>>>(
      x1b, 256, f1T, 256, tb, 256, 256, f1b, nullptr, 0, nullptr, 1 | 2, nullptr, 0);
  // u2 = tb @ fnn2 + b2 + x1
  gemm_kernel<64, 64><<<dim3(4, 48), 256, 0, stream>>>(
      tb, 256, f2T, 256, u2, 256, 256, f2b, x1f, 256, nullptr, 0, nullptr, 0);
  ln_kernel<<<NTOK / 4, 256, 0, stream>>>(u2, ln2g, ln2b, (float*)d_out, nullptr);
}

// Round 9
// 362.426 us; speedup vs baseline: 1.1926x; 1.1926x over previous
//
#include <hip/hip_runtime.h>
#include <hip/hip_bf16.h>
#include <stdint.h>

typedef __bf16 bf16x8_t __attribute__((ext_vector_type(8)));
typedef short  s16x8_t  __attribute__((ext_vector_type(8)));
typedef unsigned short u16x4_t __attribute__((ext_vector_type(4)));
typedef float  f32x4_t __attribute__((ext_vector_type(4)));

#define NTOK 3072
#define NHEAD 8
#define NSPLIT 4           // flash KV splits (96 tiles / 4 = 24 each)

__device__ __forceinline__ unsigned short f2bf(float f) {
  union { float f; uint32_t u; } v; v.f = f;
  uint32_t r = v.u + 0x7fffu + ((v.u >> 16) & 1u);
  return (unsigned short)(r >> 16);
}
__device__ __forceinline__ float bf2f(unsigned short s) {
  union { uint32_t u; float f; } v; v.u = ((uint32_t)s) << 16;
  return v.f;
}

__device__ __forceinline__ void gload_lds16(const void* g, void* lds) {
  __builtin_amdgcn_global_load_lds(
      (const __attribute__((address_space(1))) uint32_t*)g,
      (__attribute__((address_space(3))) uint32_t*)lds, 16, 0, 0);
}

// DPP lane-shuffle within 16-lane rows (compile-time ctrl)
template <int CTRL>
__device__ __forceinline__ float dpp_mv(float x) {
  union { float f; int i; } u; u.f = x;
  u.i = __builtin_amdgcn_update_dpp(0, u.i, CTRL, 0xf, 0xf, true);
  return u.f;
}
// reduce across each contiguous 16-lane group (no LDS/ds ops)
__device__ __forceinline__ float red_max16(float x) {
  x = fmaxf(x, dpp_mv<0xB1>(x));   // quad_perm xor1
  x = fmaxf(x, dpp_mv<0x4E>(x));   // quad_perm xor2
  x = fmaxf(x, dpp_mv<0x141>(x));  // row_half_mirror
  x = fmaxf(x, dpp_mv<0x140>(x));  // row_mirror
  return x;
}
__device__ __forceinline__ float red_sum16(float x) {
  x += dpp_mv<0xB1>(x);
  x += dpp_mv<0x4E>(x);
  x += dpp_mv<0x141>(x);
  x += dpp_mv<0x140>(x);
  return x;
}

// ---------------- merged prep kernel: 5 transposes + x copy, job-table ----------
__global__ void prep_all(const float* __restrict__ WQ, const float* __restrict__ WK,
                         const float* __restrict__ WV, const float* __restrict__ law,
                         const float* __restrict__ lw, const float* __restrict__ f1w,
                         const float* __restrict__ f2w, const float* __restrict__ x,
                         unsigned short* __restrict__ qkvwT, unsigned short* __restrict__ lawT,
                         unsigned short* __restrict__ lwT, unsigned short* __restrict__ f1T,
                         unsigned short* __restrict__ f2T, unsigned short* __restrict__ xa) {
  __shared__ float tile[64][65];
  const int id = blockIdx.x;
  const int t = threadIdx.x;
  if (id >= 576) {  // x copy: 64 rows x 256 cols, xa row stride 512
    int n0 = (id - 576) * 64;
    int col = (t & 63) * 4;
#pragma unroll
    for (int i = 0; i < 16; ++i) {
      int n = n0 + i * 4 + (t >> 6);
      f32x4_t v = *(const f32x4_t*)(x + (size_t)n * 256 + col);
      u16x4_t o;
#pragma unroll
      for (int j = 0; j < 4; ++j) o[j] = f2bf(v[j]);
      *(u16x4_t*)(xa + (size_t)n * 512 + col) = o;
    }
    return;
  }
  const float* src; unsigned short* dst; int sld, dld, d0, e0;
  if (id < 384) {
    int z = id >> 4, tl = id & 15;
    int op = z >> 3, hh = z & 7;
    src = ((op == 0) ? WQ : (op == 1) ? WK : WV) + (size_t)hh * 65536;
    dst = qkvwT + (size_t)z * 65536;
    sld = 256; dld = 256; d0 = (tl >> 2) * 64; e0 = (tl & 3) * 64;
  } else if (id < 512) {
    int tl = id - 384;
    src = law; dst = lawT; sld = 256; dld = 2048;
    d0 = (tl >> 2) * 64; e0 = (tl & 3) * 64;
  } else if (id < 544) {
    int tl = id - 512;
    src = lw; dst = lwT; sld = 256; dld = 512;
    d0 = (tl >> 2) * 64; e0 = (tl & 3) * 64;
  } else if (id < 560) {
    int tl = id - 544;
    src = f1w; dst = f1T; sld = 256; dld = 256;
    d0 = (tl >> 2) * 64; e0 = (tl & 3) * 64;
  } else {
    int tl = id - 560;
    src = f2w; dst = f2T; sld = 256; dld = 256;
    d0 = (tl >> 2) * 64; e0 = (tl & 3) * 64;
  }
  int tr = t >> 4, tc4 = (t & 15) * 4;
#pragma unroll
  for (int i = 0; i < 4; ++i) {
    int d = i * 16 + tr;
    f32x4_t v = *(const f32x4_t*)(src + (size_t)(d0 + d) * sld + e0 + tc4);
    tile[d][tc4] = v[0]; tile[d][tc4 + 1] = v[1]; tile[d][tc4 + 2] = v[2]; tile[d][tc4 + 3] = v[3];
  }
  __syncthreads();
#pragma unroll
  for (int i = 0; i < 4; ++i) {
    int e = i * 16 + tr;
    u16x4_t o;
#pragma unroll
    for (int j = 0; j < 4; ++j) o[j] = f2bf(tile[tc4 + j][e]);
    *(u16x4_t*)(dst + (size_t)(e0 + e) * dld + d0 + tc4) = o;
  }
}

// ---------------- generic MFMA GEMM (templated tile, swizzled LDS) --------
// flags: 1 = relu, 2 = bf16 out, 4 = (acc+bias)*rsqrt(deg[row]), 8 = f32 partial out
template <int BM, int BN>
__global__ __launch_bounds__(256, 2) void gemm_kernel(
    const unsigned short* __restrict__ A, int lda,
    const unsigned short* __restrict__ B, int ldb,
    void* __restrict__ Cout, int ldc, int Klen,
    const float* __restrict__ bias,
    const float* __restrict__ resid, int ldr,
    const float* __restrict__ deg, int flags,
    float* __restrict__ part, long pstride) {
  constexpr int WM = BM / 2, WN = BN / 2, FM = WM / 16, FN = WN / 16;
  __shared__ unsigned short As[BM * 32];
  __shared__ unsigned short Bs[BN * 32];
  const int t = threadIdx.x;
  const int w = t >> 6, l = t & 63;
  const int l15 = l & 15, lhi = l >> 4;
  const int row0 = blockIdx.y * BM, col0 = blockIdx.x * BN;
  const int wr = (w >> 1) * WM, wc = (w & 1) * WN;

  f32x4_t acc[FM][FN];
#pragma unroll
  for (int m = 0; m < FM; ++m)
#pragma unroll
    for (int n = 0; n < FN; ++n) acc[m][n] = (f32x4_t){0.f, 0.f, 0.f, 0.f};

  const int srow = l >> 2;
  const int spc  = (l & 3) * 16;
  const int kofs0 = blockIdx.z * Klen;
  const int nkt = Klen >> 5;
  for (int kt = 0; kt < nkt; ++kt) {
    const int koff = kofs0 + kt * 32;
    __syncthreads();
#pragma unroll
    for (int c = w; c < BM / 16; c += 4) {
      int ar = c * 16 + srow;
      int lcb = spc ^ (((ar >> 1) & 3) << 4);
      gload_lds16(A + (size_t)(row0 + ar) * lda + koff + (lcb >> 1), &As[c * 512]);
    }
#pragma unroll
    for (int c = w; c < BN / 16; c += 4) {
      int br = c * 16 + srow;
      int lcb = spc ^ (((br >> 1) & 3) << 4);
      gload_lds16(B + (size_t)(col0 + br) * ldb + koff + (lcb >> 1), &Bs[c * 512]);
    }
    __syncthreads();
    bf16x8_t af[FM], bfr[FN];
#pragma unroll
    for (int m = 0; m < FM; ++m) {
      int ar = wr + m * 16 + l15;
      af[m] = *(const bf16x8_t*)(&As[(ar * 64 + ((lhi * 16) ^ (((ar >> 1) & 3) << 4))) >> 1]);
    }
#pragma unroll
    for (int n = 0; n < FN; ++n) {
      int br = wc + n * 16 + l15;
      bfr[n] = *(const bf16x8_t*)(&Bs[(br * 64 + ((lhi * 16) ^ (((br >> 1) & 3) << 4))) >> 1]);
    }
#pragma unroll
    for (int m = 0; m < FM; ++m)
#pragma unroll
      for (int n = 0; n < FN; ++n)
        acc[m][n] = __builtin_amdgcn_mfma_f32_16x16x32_bf16(af[m], bfr[n], acc[m][n], 0, 0, 0);
  }

  const bool relu = flags & 1, obf = flags & 2, dsc = flags & 4, ppart = flags & 8;
#pragma unroll
  for (int m = 0; m < FM; ++m) {
#pragma unroll
    for (int r = 0; r < 4; ++r) {
      int grow = row0 + wr + m * 16 + lhi * 4 + r;
      float sc = dsc ? rsqrtf(deg[grow]) : 1.0f;
#pragma unroll
      for (int n = 0; n < FN; ++n) {
        int gcol = col0 + wc + n * 16 + l15;
        float v = acc[m][n][r];
        if (ppart) {
          part[(size_t)blockIdx.z * pstride + (size_t)grow * ldc + gcol] = v;
          continue;
        }
        if (bias) v += bias[gcol];
        v *= sc;
        if (resid) v += resid[(size_t)grow * ldr + gcol];
        if (relu) v = fmaxf(v, 0.f);
        if (obf)
          ((unsigned short*)Cout)[(size_t)grow * ldc + gcol] = f2bf(v);
        else
          ((float*)Cout)[(size_t)grow * ldc + gcol] = v;
      }
    }
  }
}

// reduce attn split-K partials: xa[n][256+d] = bf16((sum_z part + lab[d]) * rsqrt(deg[n]))
__global__ void attn_reduce(const float* __restrict__ part, const float* __restrict__ lab,
                            const float* __restrict__ deg, unsigned short* __restrict__ xa) {
  int n = blockIdx.x, d = threadIdx.x;
  float s = 0.f;
#pragma unroll
  for (int z = 0; z < 4; ++z) s += part[((size_t)z * NTOK + n) * 256 + d];
  xa[(size_t)n * 512 + 256 + d] = f2bf((s + lab[d]) * rsqrtf(deg[n]));
}

// ---------------- flash attention (split-KV, r5 structure + DPP + setprio) ----
#define VSW(e) ((((((e) >> 1) & 3) ^ (((e) >> 3) & 3))) << 4)
__global__ __launch_bounds__(256, 2) void flash_kernel(
    const unsigned short* __restrict__ qkv, unsigned short* __restrict__ pO,
    float* __restrict__ ml) {
  __shared__ unsigned short Ks[32 * 256];   // swizzled: byte ^= (row&7)<<4
  __shared__ unsigned short Vt[256 * 32];   // transposed, swizzled: byte ^= VSW(e)
  __shared__ unsigned short Ps[4][16 * 32]; // per-wave P, byte ^= ((row>>1)&3)<<4
  const int bid = blockIdx.x;
  const int hs = bid % (NHEAD * NSPLIT);
  const int qb = bid / (NHEAD * NSPLIT);
  const int h = hs / NSPLIT;
  const int split = hs % NSPLIT;
  const int q0 = qb * 64;
  const int t = threadIdx.x, w = t >> 6, l = t & 63;
  const int l15 = l & 15, lhi = l >> 4;

  const int vn0 = (t & 7) * 4;
  const int ve0 = (t >> 3) * 8;

  bf16x8_t qf[8];
  {
    const unsigned short* Qb = qkv + (size_t)(q0 + w * 16 + l15) * 6144 + h * 256 + lhi * 8;
#pragma unroll
    for (int kk = 0; kk < 8; ++kk) qf[kk] = *(const bf16x8_t*)(Qb + kk * 32);
  }
  f32x4_t o[16];
#pragma unroll
  for (int et = 0; et < 16; ++et) o[et] = (f32x4_t){0.f, 0.f, 0.f, 0.f};
  float m_run[4] = {-1e30f, -1e30f, -1e30f, -1e30f};
  float l_run[4] = {0.f, 0.f, 0.f, 0.f};

  const int nt0 = split * (96 / NSPLIT), nt1 = nt0 + 96 / NSPLIT;
  for (int nt = nt0; nt < nt1; ++nt) {
    const int kv0 = nt * 32;
    __syncthreads();
    // stage K via global_load_lds, source pre-swizzled
    {
      int rh = l >> 5;
      int pc = (l & 31) * 16;
#pragma unroll
      for (int i = 0; i < 4; ++i) {
        int c = w * 4 + i;
        int kr = c * 2 + rh;
        int lcb = pc ^ ((kr & 7) << 4);
        gload_lds16(qkv + (size_t)(kv0 + kr) * 6144 + 2048 + h * 256 + (lcb >> 1), &Ks[c * 512]);
      }
    }
    // stage V transposed (reg-staged b64 packs)
    {
      s16x8_t rv[4];
      const unsigned short* Vg = qkv + (size_t)(kv0 + vn0) * 6144 + 4096 + h * 256 + ve0;
#pragma unroll
      for (int rr = 0; rr < 4; ++rr) rv[rr] = *(const s16x8_t*)(Vg + rr * 6144);
#pragma unroll
      for (int j = 0; j < 8; ++j) {
        int e = ve0 + j;
        uint64_t pk = (uint64_t)(unsigned short)rv[0][j] |
                      ((uint64_t)(unsigned short)rv[1][j] << 16) |
                      ((uint64_t)(unsigned short)rv[2][j] << 32) |
                      ((uint64_t)(unsigned short)rv[3][j] << 48);
        int pb = e * 64 + ((vn0 * 2) ^ VSW(e));
        *(uint64_t*)(&Vt[pb >> 1]) = pk;
      }
    }
    __syncthreads();

    // S = Q Kt : 16x32 per wave
    f32x4_t s[2];
#pragma unroll
    for (int ni = 0; ni < 2; ++ni) s[ni] = (f32x4_t){0.f, 0.f, 0.f, 0.f};
    __builtin_amdgcn_s_setprio(1);
#pragma unroll
    for (int kk = 0; kk < 8; ++kk) {
#pragma unroll
      for (int ni = 0; ni < 2; ++ni) {
        int br = ni * 16 + l15;
        bf16x8_t kb = *(const bf16x8_t*)(&Ks[(br * 512 + ((kk * 64 + lhi * 16) ^ ((br & 7) << 4))) >> 1]);
        s[ni] = __builtin_amdgcn_mfma_f32_16x16x32_bf16(qf[kk], kb, s[ni], 0, 0, 0);
      }
    }
    __builtin_amdgcn_s_setprio(0);

    // online softmax (DPP 16-lane reduces)
    float p[2][4];
    float alpha[4];
#pragma unroll
    for (int r = 0; r < 4; ++r) {
      int grow = q0 + w * 16 + lhi * 4 + r;
      float sv0 = s[0][r] * 0.0625f;
      float sv1 = s[1][r] * 0.0625f;
      if (kv0 + l15 == grow) sv0 = -1e30f;
      if (kv0 + 16 + l15 == grow) sv1 = -1e30f;
      float mx = red_max16(fmaxf(sv0, sv1));
      float mn = fmaxf(m_run[r], mx);
      alpha[r] = __expf(m_run[r] - mn);
      m_run[r] = mn;
      float pv0 = __expf(sv0 - mn);
      float pv1 = __expf(sv1 - mn);
      p[0][r] = pv0; p[1][r] = pv1;
      float ls = red_sum16(pv0 + pv1);
      l_run[r] = l_run[r] * alpha[r] + ls;
    }
#pragma unroll
    for (int et = 0; et < 16; ++et)
#pragma unroll
      for (int r = 0; r < 4; ++r) o[et][r] *= alpha[r];

    // P -> per-wave LDS (bf16), then PV
    unsigned short* Pw = &Ps[w][0];
#pragma unroll
    for (int ni = 0; ni < 2; ++ni)
#pragma unroll
      for (int r = 0; r < 4; ++r) {
        int prow = lhi * 4 + r;
        int pb = prow * 64 + ((((ni * 16 + l15) * 2)) ^ (((prow >> 1) & 3) << 4));
        Pw[pb >> 1] = f2bf(p[ni][r]);
      }
    bf16x8_t pa = *(const bf16x8_t*)(&Pw[(l15 * 64 + ((lhi * 16) ^ (((l15 >> 1) & 3) << 4))) >> 1]);
    __builtin_amdgcn_s_setprio(1);
#pragma unroll
    for (int et = 0; et < 16; ++et) {
      int er = et * 16 + l15;
      bf16x8_t vb = *(const bf16x8_t*)(&Vt[(er * 64 + ((lhi * 16) ^ VSW(er))) >> 1]);
      o[et] = __builtin_amdgcn_mfma_f32_16x16x32_bf16(pa, vb, o[et], 0, 0, 0);
    }
    __builtin_amdgcn_s_setprio(0);
  }

  const size_t sh = (size_t)(split * NHEAD + h);
#pragma unroll
  for (int et = 0; et < 16; ++et)
#pragma unroll
    for (int r = 0; r < 4; ++r) {
      int grow = q0 + w * 16 + lhi * 4 + r;
      pO[(sh * NTOK + grow) * 256 + et * 16 + l15] = f2bf(o[et][r]);
    }
  if (l15 == 0) {
#pragma unroll
    for (int r = 0; r < 4; ++r) {
      int grow = q0 + w * 16 + lhi * 4 + r;
      ml[(sh * NTOK + grow) * 2] = m_run[r];
      ml[(sh * NTOK + grow) * 2 + 1] = l_run[r];
    }
  }
}

// combine splits: acat[n][h*256+e] = sum_s w_s O_s / sum_s w_s l_s
__global__ void flash_combine(const unsigned short* __restrict__ pO,
                              const float* __restrict__ ml,
                              unsigned short* __restrict__ acat) {
  int n = blockIdx.x, t = threadIdx.x;
  int h = t >> 5, e0 = (t & 31) * 8;
  float ms[NSPLIT], ls[NSPLIT];
  float M = -1e30f;
#pragma unroll
  for (int s = 0; s < NSPLIT; ++s) {
    size_t b = ((size_t)(s * NHEAD + h) * NTOK + n) * 2;
    ms[s] = ml[b]; ls[s] = ml[b + 1];
    M = fmaxf(M, ms[s]);
  }
  float den = 0.f;
  float num[8];
#pragma unroll
  for (int j = 0; j < 8; ++j) num[j] = 0.f;
#pragma unroll
  for (int s = 0; s < NSPLIT; ++s) {
    float ws = __expf(ms[s] - M);
    den += ws * ls[s];
    s16x8_t ov = *(const s16x8_t*)(pO + ((size_t)(s * NHEAD + h) * NTOK + n) * 256 + e0);
#pragma unroll
    for (int j = 0; j < 8; ++j) num[j] += ws * bf2f((unsigned short)ov[j]);
  }
  float rden = 1.0f / den;
  s16x8_t out;
#pragma unroll
  for (int j = 0; j < 8; ++j) out[j] = (short)f2bf(num[j] * rden);
  *(s16x8_t*)(acat + (size_t)n * 2048 + h * 256 + e0) = out;
}

// ---------------- fused tail: u1 GEMM + LN1 + fnn1 + fnn2 + LN2 ----------------
// 192 blocks x 16 rows. Per block: u1 = xa@lwT + lb + x -> LN1 -> x1 (f32 regs +
// bf16 LDS) -> relu(x1@f1T + f1b) -> @f2T + f2b + x1 -> LN2 -> out (f32).
__global__ __launch_bounds__(256, 2) void tail_fused(
    const unsigned short* __restrict__ xa, const unsigned short* __restrict__ lwT,
    const unsigned short* __restrict__ f1T, const unsigned short* __restrict__ f2T,
    const float* __restrict__ x, const float* __restrict__ lb,
    const float* __restrict__ ln1g, const float* __restrict__ ln1b,
    const float* __restrict__ f1b, const float* __restrict__ f2b,
    const float* __restrict__ ln2g, const float* __restrict__ ln2b,
    float* __restrict__ out) {
  __shared__ unsigned short As[16 * 32];    // 1KB A chunk
  __shared__ unsigned short Bs[256 * 32];   // 16KB B chunk
  __shared__ unsigned short Xs[16 * 256];   // 8KB x1/tb bf16, byte ^= (row&7)<<4
  __shared__ float red[16][4][2];           // per-row (sum, sumsq) per wave
  const int t = threadIdx.x, w = t >> 6, l = t & 63;
  const int l15 = l & 15, lhi = l >> 4;
  const int row0 = blockIdx.x * 16;
  const int wc = w * 64;
  const int srow = l >> 2, spc = (l & 3) * 16;

  // ---- phase 1: u1 = xa @ lwT (K=512) ----
  f32x4_t acc[4];
#pragma unroll
  for (int n = 0; n < 4; ++n) acc[n] = (f32x4_t){0.f, 0.f, 0.f, 0.f};
  for (int kt = 0; kt < 16; ++kt) {
    __syncthreads();
    if (w == 0) {
      int ar = srow;
      int lcb = spc ^ (((ar >> 1) & 3) << 4);
      gload_lds16(xa + (size_t)(row0 + ar) * 512 + kt * 32 + (lcb >> 1), &As[0]);
    }
#pragma unroll
    for (int c = w; c < 16; c += 4) {
      int br = c * 16 + srow;
      int lcb = spc ^ (((br >> 1) & 3) << 4);
      gload_lds16(lwT + (size_t)br * 512 + kt * 32 + (lcb >> 1), &Bs[c * 512]);
    }
    __syncthreads();
    bf16x8_t af = *(const bf16x8_t*)(&As[(l15 * 64 + ((lhi * 16) ^ (((l15 >> 1) & 3) << 4))) >> 1]);
#pragma unroll
    for (int n = 0; n < 4; ++n) {
      int br = wc + n * 16 + l15;
      bf16x8_t bfr = *(const bf16x8_t*)(&Bs[(br * 64 + ((lhi * 16) ^ (((br >> 1) & 3) << 4))) >> 1]);
      acc[n] = __builtin_amdgcn_mfma_f32_16x16x32_bf16(af, bfr, acc[n], 0, 0, 0);
    }
  }
  // epilogue: + lb + x, then LN1
  float x1v[4][4];   // [n][r]
#pragma unroll
  for (int r = 0; r < 4; ++r) {
    int grow = row0 + lhi * 4 + r;
#pragma unroll
    for (int n = 0; n < 4; ++n) {
      int col = wc + n * 16 + l15;
      x1v[n][r] = acc[n][r] + lb[col] + x[(size_t)grow * 256 + col];
    }
  }
#pragma unroll
  for (int r = 0; r < 4; ++r) {
    float s = x1v[0][r] + x1v[1][r] + x1v[2][r] + x1v[3][r];
    float q = x1v[0][r] * x1v[0][r] + x1v[1][r] * x1v[1][r] +
              x1v[2][r] * x1v[2][r] + x1v[3][r] * x1v[3][r];
    s = red_sum16(s); q = red_sum16(q);
    if (l15 == 0) { red[lhi * 4 + r][w][0] = s; red[lhi * 4 + r][w][1] = q; }
  }
  __syncthreads();
#pragma unroll
  for (int r = 0; r < 4; ++r) {
    int row = lhi * 4 + r;
    float s = red[row][0][0] + red[row][1][0] + red[row][2][0] + red[row][3][0];
    float q = red[row][0][1] + red[row][1][1] + red[row][2][1] + red[row][3][1];
    float mu = s * (1.0f / 256.0f);
    float var = q * (1.0f / 256.0f) - mu * mu;
    float rstd = rsqrtf(var + 1e-5f);
#pragma unroll
    for (int n = 0; n < 4; ++n) {
      int col = wc + n * 16 + l15;
      float xv = (x1v[n][r] - mu) * rstd * ln1g[col] + ln1b[col];
      x1v[n][r] = xv;
      int pb = row * 512 + ((col * 2) ^ ((row & 7) << 4));
      Xs[pb >> 1] = f2bf(xv);
    }
  }

  // ---- phase 2: t = relu(x1 @ f1T + f1b) (K=256) ----
  f32x4_t acc2[4];
#pragma unroll
  for (int n = 0; n < 4; ++n) acc2[n] = (f32x4_t){0.f, 0.f, 0.f, 0.f};
  for (int kt = 0; kt < 8; ++kt) {
    __syncthreads();   // covers Xs publish (kt=0) and Bs reuse
#pragma unroll
    for (int c = w; c < 16; c += 4) {
      int br = c * 16 + srow;
      int lcb = spc ^ (((br >> 1) & 3) << 4);
      gload_lds16(f1T + (size_t)br * 256 + kt * 32 + (lcb >> 1), &Bs[c * 512]);
    }
    __syncthreads();
    bf16x8_t af = *(const bf16x8_t*)(&Xs[(l15 * 512 + (((kt * 32 + lhi * 8) * 2) ^ ((l15 & 7) << 4))) >> 1]);
#pragma unroll
    for (int n = 0; n < 4; ++n) {
      int br = wc + n * 16 + l15;
      bf16x8_t bfr = *(const bf16x8_t*)(&Bs[(br * 64 + ((lhi * 16) ^ (((br >> 1) & 3) << 4))) >> 1]);
      acc2[n] = __builtin_amdgcn_mfma_f32_16x16x32_bf16(af, bfr, acc2[n], 0, 0, 0);
    }
  }
  __syncthreads();   // all Xs(x1) reads done -> safe to overwrite with tb
#pragma unroll
  for (int r = 0; r < 4; ++r) {
    int row = lhi * 4 + r;
#pragma unroll
    for (int n = 0; n < 4; ++n) {
      int col = wc + n * 16 + l15;
      float v = fmaxf(acc2[n][r] + f1b[col], 0.f);
      int pb = row * 512 + ((col * 2) ^ ((row & 7) << 4));
      Xs[pb >> 1] = f2bf(v);
    }
  }

  // ---- phase 3: u2 = tb @ f2T + f2b + x1 (K=256), then LN2 ----
  f32x4_t acc3[4];
#pragma unroll
  for (int n = 0; n < 4; ++n) acc3[n] = (f32x4_t){0.f, 0.f, 0.f, 0.f};
  for (int kt = 0; kt < 8; ++kt) {
    __syncthreads();
#pragma unroll
    for (int c = w; c < 16; c += 4) {
      int br = c * 16 + srow;
      int lcb = spc ^ (((br >> 1) & 3) << 4);
      gload_lds16(f2T + (size_t)br * 256 + kt * 32 + (lcb >> 1), &Bs[c * 512]);
    }
    __syncthreads();
    bf16x8_t af = *(const bf16x8_t*)(&Xs[(l15 * 512 + (((kt * 32 + lhi * 8) * 2) ^ ((l15 & 7) << 4))) >> 1]);
#pragma unroll
    for (int n = 0; n < 4; ++n) {
      int br = wc + n * 16 + l15;
      bf16x8_t bfr = *(const bf16x8_t*)(&Bs[(br * 64 + ((lhi * 16) ^ (((br >> 1) & 3) << 4))) >> 1]);
      acc3[n] = __builtin_amdgcn_mfma_f32_16x16x32_bf16(af, bfr, acc3[n], 0, 0, 0);
    }
  }
  float u2v[4][4];
#pragma unroll
  for (int r = 0; r < 4; ++r) {
#pragma unroll
    for (int n = 0; n < 4; ++n) {
      int col = wc + n * 16 + l15;
      u2v[n][r] = acc3[n][r] + f2b[col] + x1v[n][r];
    }
  }
  __syncthreads();
#pragma unroll
  for (int r = 0; r < 4; ++r) {
    float s = u2v[0][r] + u2v[1][r] + u2v[2][r] + u2v[3][r];
    float q = u2v[0][r] * u2v[0][r] + u2v[1][r] * u2v[1][r] +
              u2v[2][r] * u2v[2][r] + u2v[3][r] * u2v[3][r];
    s = red_sum16(s); q = red_sum16(q);
    if (l15 == 0) { red[lhi * 4 + r][w][0] = s; red[lhi * 4 + r][w][1] = q; }
  }
  __syncthreads();
#pragma unroll
  for (int r = 0; r < 4; ++r) {
    int row = lhi * 4 + r;
    int grow = row0 + row;
    float s = red[row][0][0] + red[row][1][0] + red[row][2][0] + red[row][3][0];
    float q = red[row][0][1] + red[row][1][1] + red[row][2][1] + red[row][3][1];
    float mu = s * (1.0f / 256.0f);
    float var = q * (1.0f / 256.0f) - mu * mu;
    float rstd = rsqrtf(var + 1e-5f);
#pragma unroll
    for (int n = 0; n < 4; ++n) {
      int col = wc + n * 16 + l15;
      out[(size_t)grow * 256 + col] = (u2v[n][r] - mu) * rstd * ln2g[col] + ln2b[col];
    }
  }
}

// ---------------- launcher ----------------
extern "C" void kernel_launch(void* const* d_in, const int* in_sizes, int n_in,
                              void* d_out, int out_size, void* d_ws, size_t ws_size,
                              hipStream_t stream) {
  const float* x    = (const float*)d_in[0];
  const float* deg  = (const float*)d_in[1];
  const float* WQ   = (const float*)d_in[2];
  const float* WK   = (const float*)d_in[3];
  const float* WV   = (const float*)d_in[4];
  const float* law  = (const float*)d_in[5];
  const float* lab  = (const float*)d_in[6];
  const float* lw   = (const float*)d_in[7];
  const float* lb   = (const float*)d_in[8];
  const float* ln1g = (const float*)d_in[9];
  const float* ln1b = (const float*)d_in[10];
  const float* f1w  = (const float*)d_in[11];
  const float* f1b  = (const float*)d_in[12];
  const float* f2w  = (const float*)d_in[13];
  const float* f2b  = (const float*)d_in[14];
  const float* ln2g = (const float*)d_in[15];
  const float* ln2b = (const float*)d_in[16];

  char* ws = (char*)d_ws;
  size_t off = 0;
  auto alloc = [&](size_t bytes) {
    void* p = ws + off;
    off += (bytes + 255) & ~(size_t)255;
    return p;
  };
  unsigned short* qkvwT = (unsigned short*)alloc((size_t)6144 * 256 * 2);
  unsigned short* lawT  = (unsigned short*)alloc((size_t)256 * 2048 * 2);
  unsigned short* lwT   = (unsigned short*)alloc((size_t)256 * 512 * 2);
  unsigned short* f1T   = (unsigned short*)alloc((size_t)256 * 256 * 2);
  unsigned short* f2T   = (unsigned short*)alloc((size_t)256 * 256 * 2);
  unsigned short* xa    = (unsigned short*)alloc((size_t)NTOK * 512 * 2);
  unsigned short* qkv   = (unsigned short*)alloc((size_t)NTOK * 6144 * 2);
  unsigned short* acat  = (unsigned short*)alloc((size_t)NTOK * 2048 * 2);
  unsigned short* pO    = (unsigned short*)alloc((size_t)NSPLIT * NHEAD * NTOK * 256 * 2);
  float*          mlp   = (float*)alloc((size_t)NSPLIT * NHEAD * NTOK * 2 * 4);
  float*          apart = (float*)alloc((size_t)4 * NTOK * 256 * 4);

  prep_all<<<624, 256, 0, stream>>>(WQ, WK, WV, law, lw, f1w, f2w, x,
                                    qkvwT, lawT, lwT, f1T, f2T, xa);

  // QKV: (3072x256)@(256x6144) -> qkv bf16
  gemm_kernel<128, 128><<<dim3(48, 24), 256, 0, stream>>>(
      xa, 512, qkvwT, 256, qkv, 6144, 256, nullptr, nullptr, 0, nullptr, 2, nullptr, 0);

  flash_kernel<<<NTOK / 64 * NHEAD * NSPLIT, 256, 0, stream>>>(qkv, pO, mlp);
  flash_combine<<<NTOK, 256, 0, stream>>>(pO, mlp, acat);

  // attn_out split-K x4 -> f32 partials, then reduce (+bias)*rsqrt(deg) -> xa[:,256:512]
  gemm_kernel<64, 64><<<dim3(4, 48, 4), 256, 0, stream>>>(
      acat, 2048, lawT, 2048, nullptr, 256, 512, nullptr, nullptr, 0, nullptr, 8,
      apart, (long)NTOK * 256);
  attn_reduce<<<NTOK, 256, 0, stream>>>(apart, lab, deg, xa);

  // fused tail: u1 -> LN1 -> fnn1 -> fnn2 -> LN2 -> out
  tail_fused<<<NTOK / 16, 256, 0, stream>>>(
      xa, lwT, f1T, f2T, x, lb, ln1g, ln1b, f1b, f2b, ln2g, ln2b, (float*)d_out);
}

// Round 10
// 324.756 us; speedup vs baseline: 1.3310x; 1.1160x over previous
//
#include <hip/hip_runtime.h>
#include <hip/hip_bf16.h>
#include <stdint.h>

typedef __bf16 bf16x8_t __attribute__((ext_vector_type(8)));
typedef short  s16x8_t  __attribute__((ext_vector_type(8)));
typedef unsigned short u16x4_t __attribute__((ext_vector_type(4)));
typedef unsigned short u16x8_t __attribute__((ext_vector_type(8)));
typedef float  f32x4_t __attribute__((ext_vector_type(4)));

#define NTOK 3072
#define NHEAD 8
#define NSPLIT 4           // flash KV splits (48 x 64-tiles / 4 = 12 each)

__device__ __forceinline__ unsigned short f2bf(float f) {
  union { float f; uint32_t u; } v; v.f = f;
  uint32_t r = v.u + 0x7fffu + ((v.u >> 16) & 1u);
  return (unsigned short)(r >> 16);
}
__device__ __forceinline__ float bf2f(unsigned short s) {
  union { uint32_t u; float f; } v; v.u = ((uint32_t)s) << 16;
  return v.f;
}

__device__ __forceinline__ void gload_lds16(const void* g, void* lds) {
  __builtin_amdgcn_global_load_lds(
      (const __attribute__((address_space(1))) uint32_t*)g,
      (__attribute__((address_space(3))) uint32_t*)lds, 16, 0, 0);
}

// DPP lane-shuffle within 16-lane rows (compile-time ctrl)
template <int CTRL>
__device__ __forceinline__ float dpp_mv(float x) {
  union { float f; int i; } u; u.f = x;
  u.i = __builtin_amdgcn_update_dpp(0, u.i, CTRL, 0xf, 0xf, true);
  return u.f;
}
__device__ __forceinline__ float red_max16(float x) {
  x = fmaxf(x, dpp_mv<0xB1>(x));
  x = fmaxf(x, dpp_mv<0x4E>(x));
  x = fmaxf(x, dpp_mv<0x141>(x));
  x = fmaxf(x, dpp_mv<0x140>(x));
  return x;
}
__device__ __forceinline__ float red_sum16(float x) {
  x += dpp_mv<0xB1>(x);
  x += dpp_mv<0x4E>(x);
  x += dpp_mv<0x141>(x);
  x += dpp_mv<0x140>(x);
  return x;
}

// ---------------- merged prep kernel: 5 transposes + x copy, job-table ----------
__global__ void prep_all(const float* __restrict__ WQ, const float* __restrict__ WK,
                         const float* __restrict__ WV, const float* __restrict__ law,
                         const float* __restrict__ lw, const float* __restrict__ f1w,
                         const float* __restrict__ f2w, const float* __restrict__ x,
                         unsigned short* __restrict__ qkvwT, unsigned short* __restrict__ lawT,
                         unsigned short* __restrict__ lwT, unsigned short* __restrict__ f1T,
                         unsigned short* __restrict__ f2T, unsigned short* __restrict__ xa) {
  __shared__ float tile[64][65];
  const int id = blockIdx.x;
  const int t = threadIdx.x;
  if (id >= 576) {  // x copy: 64 rows x 256 cols, xa row stride 512
    int n0 = (id - 576) * 64;
    int col = (t & 63) * 4;
#pragma unroll
    for (int i = 0; i < 16; ++i) {
      int n = n0 + i * 4 + (t >> 6);
      f32x4_t v = *(const f32x4_t*)(x + (size_t)n * 256 + col);
      u16x4_t o;
#pragma unroll
      for (int j = 0; j < 4; ++j) o[j] = f2bf(v[j]);
      *(u16x4_t*)(xa + (size_t)n * 512 + col) = o;
    }
    return;
  }
  const float* src; unsigned short* dst; int sld, dld, d0, e0;
  if (id < 384) {
    int z = id >> 4, tl = id & 15;
    int op = z >> 3, hh = z & 7;
    src = ((op == 0) ? WQ : (op == 1) ? WK : WV) + (size_t)hh * 65536;
    dst = qkvwT + (size_t)z * 65536;
    sld = 256; dld = 256; d0 = (tl >> 2) * 64; e0 = (tl & 3) * 64;
  } else if (id < 512) {
    int tl = id - 384;
    src = law; dst = lawT; sld = 256; dld = 2048;
    d0 = (tl >> 2) * 64; e0 = (tl & 3) * 64;
  } else if (id < 544) {
    int tl = id - 512;
    src = lw; dst = lwT; sld = 256; dld = 512;
    d0 = (tl >> 2) * 64; e0 = (tl & 3) * 64;
  } else if (id < 560) {
    int tl = id - 544;
    src = f1w; dst = f1T; sld = 256; dld = 256;
    d0 = (tl >> 2) * 64; e0 = (tl & 3) * 64;
  } else {
    int tl = id - 560;
    src = f2w; dst = f2T; sld = 256; dld = 256;
    d0 = (tl >> 2) * 64; e0 = (tl & 3) * 64;
  }
  int tr = t >> 4, tc4 = (t & 15) * 4;
#pragma unroll
  for (int i = 0; i < 4; ++i) {
    int d = i * 16 + tr;
    f32x4_t v = *(const f32x4_t*)(src + (size_t)(d0 + d) * sld + e0 + tc4);
    tile[d][tc4] = v[0]; tile[d][tc4 + 1] = v[1]; tile[d][tc4 + 2] = v[2]; tile[d][tc4 + 3] = v[3];
  }
  __syncthreads();
#pragma unroll
  for (int i = 0; i < 4; ++i) {
    int e = i * 16 + tr;
    u16x4_t o;
#pragma unroll
    for (int j = 0; j < 4; ++j) o[j] = f2bf(tile[tc4 + j][e]);
    *(u16x4_t*)(dst + (size_t)(e0 + e) * dld + d0 + tc4) = o;
  }
}

// ---------------- generic MFMA GEMM (templated tile, swizzled LDS) --------
// flags: 1 = relu, 2 = bf16 out, 4 = (acc+bias)*rsqrt(deg[row]), 8 = f32 partial out
template <int BM, int BN>
__global__ __launch_bounds__(256, 2) void gemm_kernel(
    const unsigned short* __restrict__ A, int lda,
    const unsigned short* __restrict__ B, int ldb,
    void* __restrict__ Cout, int ldc, int Klen,
    const float* __restrict__ bias,
    const float* __restrict__ resid, int ldr,
    const float* __restrict__ deg, int flags,
    float* __restrict__ part, long pstride) {
  constexpr int WM = BM / 2, WN = BN / 2, FM = WM / 16, FN = WN / 16;
  __shared__ unsigned short As[BM * 32];
  __shared__ unsigned short Bs[BN * 32];
  const int t = threadIdx.x;
  const int w = t >> 6, l = t & 63;
  const int l15 = l & 15, lhi = l >> 4;
  const int row0 = blockIdx.y * BM, col0 = blockIdx.x * BN;
  const int wr = (w >> 1) * WM, wc = (w & 1) * WN;

  f32x4_t acc[FM][FN];
#pragma unroll
  for (int m = 0; m < FM; ++m)
#pragma unroll
    for (int n = 0; n < FN; ++n) acc[m][n] = (f32x4_t){0.f, 0.f, 0.f, 0.f};

  const int srow = l >> 2;
  const int spc  = (l & 3) * 16;
  const int kofs0 = blockIdx.z * Klen;
  const int nkt = Klen >> 5;
  for (int kt = 0; kt < nkt; ++kt) {
    const int koff = kofs0 + kt * 32;
    __syncthreads();
#pragma unroll
    for (int c = w; c < BM / 16; c += 4) {
      int ar = c * 16 + srow;
      int lcb = spc ^ (((ar >> 1) & 3) << 4);
      gload_lds16(A + (size_t)(row0 + ar) * lda + koff + (lcb >> 1), &As[c * 512]);
    }
#pragma unroll
    for (int c = w; c < BN / 16; c += 4) {
      int br = c * 16 + srow;
      int lcb = spc ^ (((br >> 1) & 3) << 4);
      gload_lds16(B + (size_t)(col0 + br) * ldb + koff + (lcb >> 1), &Bs[c * 512]);
    }
    __syncthreads();
    bf16x8_t af[FM], bfr[FN];
#pragma unroll
    for (int m = 0; m < FM; ++m) {
      int ar = wr + m * 16 + l15;
      af[m] = *(const bf16x8_t*)(&As[(ar * 64 + ((lhi * 16) ^ (((ar >> 1) & 3) << 4))) >> 1]);
    }
#pragma unroll
    for (int n = 0; n < FN; ++n) {
      int br = wc + n * 16 + l15;
      bfr[n] = *(const bf16x8_t*)(&Bs[(br * 64 + ((lhi * 16) ^ (((br >> 1) & 3) << 4))) >> 1]);
    }
#pragma unroll
    for (int m = 0; m < FM; ++m)
#pragma unroll
      for (int n = 0; n < FN; ++n)
        acc[m][n] = __builtin_amdgcn_mfma_f32_16x16x32_bf16(af[m], bfr[n], acc[m][n], 0, 0, 0);
  }

  const bool relu = flags & 1, obf = flags & 2, dsc = flags & 4, ppart = flags & 8;
#pragma unroll
  for (int m = 0; m < FM; ++m) {
#pragma unroll
    for (int r = 0; r < 4; ++r) {
      int grow = row0 + wr + m * 16 + lhi * 4 + r;
      float sc = dsc ? rsqrtf(deg[grow]) : 1.0f;
#pragma unroll
      for (int n = 0; n < FN; ++n) {
        int gcol = col0 + wc + n * 16 + l15;
        float v = acc[m][n][r];
        if (ppart) {
          part[(size_t)blockIdx.z * pstride + (size_t)grow * ldc + gcol] = v;
          continue;
        }
        if (bias) v += bias[gcol];
        v *= sc;
        if (resid) v += resid[(size_t)grow * ldr + gcol];
        if (relu) v = fmaxf(v, 0.f);
        if (obf)
          ((unsigned short*)Cout)[(size_t)grow * ldc + gcol] = f2bf(v);
        else
          ((float*)Cout)[(size_t)grow * ldc + gcol] = v;
      }
    }
  }
}

// reduce attn split-K partials: xa[n][256+d] = bf16((sum_z part + lab[d]) * rsqrt(deg[n]))
__global__ void attn_reduce(const float* __restrict__ part, const float* __restrict__ lab,
                            const float* __restrict__ deg, unsigned short* __restrict__ xa) {
  int n = blockIdx.x, d = threadIdx.x;
  float s = 0.f;
#pragma unroll
  for (int z = 0; z < 4; ++z) s += part[((size_t)z * NTOK + n) * 256 + d];
  xa[(size_t)n * 512 + 256 + d] = f2bf((s + lab[d]) * rsqrtf(deg[n]));
}

// ---------------- flash attention (split-KV, KVBLK=64, DPP + setprio) ----
// Vt row = 64 kv x 2B = 128B; swizzle keeps reads <=2-way, writes slot-uniform.
#define VSW64(e) (((((e) & 7) ^ (((e) >> 3) & 7))) << 4)
#define PSW(r)   (((r) & 7) << 4)
__global__ __launch_bounds__(256, 2) void flash_kernel(
    const unsigned short* __restrict__ qkv, unsigned short* __restrict__ pO,
    float* __restrict__ ml) {
  __shared__ unsigned short Ks[64 * 256];   // 32KB, byte ^= (row&7)<<4
  __shared__ unsigned short Vt[256 * 64];   // 32KB transposed, byte ^= VSW64(e)
  __shared__ unsigned short Ps[4][16 * 64]; // 8KB per-wave P, byte ^= PSW(row)
  const int bid = blockIdx.x;
  const int hs = bid % (NHEAD * NSPLIT);
  const int qb = bid / (NHEAD * NSPLIT);
  const int h = hs / NSPLIT;
  const int split = hs % NSPLIT;
  const int q0 = qb * 64;
  const int t = threadIdx.x, w = t >> 6, l = t & 63;
  const int l15 = l & 15, lhi = l >> 4;

  const int vn0 = (t & 7) * 8;        // V-staging: 8 kv rows
  const int ve0 = (t >> 3) * 8;       // 8 features

  bf16x8_t qf[8];
  {
    const unsigned short* Qb = qkv + (size_t)(q0 + w * 16 + l15) * 6144 + h * 256 + lhi * 8;
#pragma unroll
    for (int kk = 0; kk < 8; ++kk) qf[kk] = *(const bf16x8_t*)(Qb + kk * 32);
  }
  f32x4_t o[16];
#pragma unroll
  for (int et = 0; et < 16; ++et) o[et] = (f32x4_t){0.f, 0.f, 0.f, 0.f};
  float m_run[4] = {-1e30f, -1e30f, -1e30f, -1e30f};
  float l_run[4] = {0.f, 0.f, 0.f, 0.f};

  for (int it = 0; it < 12; ++it) {
    const int kv0 = (split * 12 + it) * 64;
    __syncthreads();
    // stage K (64 rows) via global_load_lds, source pre-swizzled
    {
      int rh = l >> 5;
      int pc = (l & 31) * 16;
#pragma unroll
      for (int i = 0; i < 8; ++i) {
        int c = w * 8 + i;
        int kr = c * 2 + rh;
        int lcb = pc ^ ((kr & 7) << 4);
        gload_lds16(qkv + (size_t)(kv0 + kr) * 6144 + 2048 + h * 256 + (lcb >> 1), &Ks[c * 512]);
      }
    }
    // stage V transposed (reg-staged, 16B packed writes)
    {
      s16x8_t rv[8];
      const unsigned short* Vg = qkv + (size_t)(kv0 + vn0) * 6144 + 4096 + h * 256 + ve0;
#pragma unroll
      for (int rr = 0; rr < 8; ++rr) rv[rr] = *(const s16x8_t*)(Vg + rr * 6144);
#pragma unroll
      for (int j = 0; j < 8; ++j) {
        int e = ve0 + j;
        u16x8_t pk;
#pragma unroll
        for (int rr = 0; rr < 8; ++rr) pk[rr] = (unsigned short)rv[rr][j];
        int pb = e * 128 + ((vn0 * 2) ^ VSW64(e));
        *(u16x8_t*)(&Vt[pb >> 1]) = pk;
      }
    }
    __syncthreads();

    // S = Q Kt : 16x64 per wave
    f32x4_t s[4];
#pragma unroll
    for (int ni = 0; ni < 4; ++ni) s[ni] = (f32x4_t){0.f, 0.f, 0.f, 0.f};
    __builtin_amdgcn_s_setprio(1);
#pragma unroll
    for (int kk = 0; kk < 8; ++kk) {
#pragma unroll
      for (int ni = 0; ni < 4; ++ni) {
        int br = ni * 16 + l15;
        bf16x8_t kb = *(const bf16x8_t*)(&Ks[(br * 512 + ((kk * 64 + lhi * 16) ^ ((br & 7) << 4))) >> 1]);
        s[ni] = __builtin_amdgcn_mfma_f32_16x16x32_bf16(qf[kk], kb, s[ni], 0, 0, 0);
      }
    }
    __builtin_amdgcn_s_setprio(0);

    // online softmax (DPP 16-lane reduces)
    float p[4][4];
    float alpha[4];
#pragma unroll
    for (int r = 0; r < 4; ++r) {
      int grow = q0 + w * 16 + lhi * 4 + r;
      float sv[4];
      float mx0 = -1e30f, mx1 = -1e30f;
#pragma unroll
      for (int ni = 0; ni < 4; ++ni) {
        float x = s[ni][r] * 0.0625f;
        if (kv0 + ni * 16 + l15 == grow) x = -1e30f;
        sv[ni] = x;
        if (ni & 1) mx1 = fmaxf(mx1, x); else mx0 = fmaxf(mx0, x);
      }
      float mx = red_max16(fmaxf(mx0, mx1));
      float mn = fmaxf(m_run[r], mx);
      alpha[r] = __expf(m_run[r] - mn);
      m_run[r] = mn;
      float ls = 0.f;
#pragma unroll
      for (int ni = 0; ni < 4; ++ni) {
        float pv = __expf(sv[ni] - mn);
        p[ni][r] = pv;
        ls += pv;
      }
      ls = red_sum16(ls);
      l_run[r] = l_run[r] * alpha[r] + ls;
    }
#pragma unroll
    for (int et = 0; et < 16; ++et)
#pragma unroll
      for (int r = 0; r < 4; ++r) o[et][r] *= alpha[r];

    // P -> per-wave LDS (bf16), then PV (two k-slices)
    unsigned short* Pw = &Ps[w][0];
#pragma unroll
    for (int ni = 0; ni < 4; ++ni)
#pragma unroll
      for (int r = 0; r < 4; ++r) {
        int prow = lhi * 4 + r;
        int pb = prow * 128 + (((ni * 16 + l15) * 2) ^ PSW(prow));
        Pw[pb >> 1] = f2bf(p[ni][r]);
      }
    bf16x8_t pa0 = *(const bf16x8_t*)(&Pw[(l15 * 128 + ((lhi * 16) ^ PSW(l15))) >> 1]);
    bf16x8_t pa1 = *(const bf16x8_t*)(&Pw[(l15 * 128 + ((64 + lhi * 16) ^ PSW(l15))) >> 1]);
    __builtin_amdgcn_s_setprio(1);
#pragma unroll
    for (int et = 0; et < 16; ++et) {
      int er = et * 16 + l15;
      bf16x8_t vb0 = *(const bf16x8_t*)(&Vt[(er * 128 + ((lhi * 16) ^ VSW64(er))) >> 1]);
      bf16x8_t vb1 = *(const bf16x8_t*)(&Vt[(er * 128 + ((64 + lhi * 16) ^ VSW64(er))) >> 1]);
      o[et] = __builtin_amdgcn_mfma_f32_16x16x32_bf16(pa0, vb0, o[et], 0, 0, 0);
      o[et] = __builtin_amdgcn_mfma_f32_16x16x32_bf16(pa1, vb1, o[et], 0, 0, 0);
    }
    __builtin_amdgcn_s_setprio(0);
  }

  const size_t sh = (size_t)(split * NHEAD + h);
#pragma unroll
  for (int et = 0; et < 16; ++et)
#pragma unroll
    for (int r = 0; r < 4; ++r) {
      int grow = q0 + w * 16 + lhi * 4 + r;
      pO[(sh * NTOK + grow) * 256 + et * 16 + l15] = f2bf(o[et][r]);
    }
  if (l15 == 0) {
#pragma unroll
    for (int r = 0; r < 4; ++r) {
      int grow = q0 + w * 16 + lhi * 4 + r;
      ml[(sh * NTOK + grow) * 2] = m_run[r];
      ml[(sh * NTOK + grow) * 2 + 1] = l_run[r];
    }
  }
}

// combine splits: acat[n][h*256+e] = sum_s w_s O_s / sum_s w_s l_s
__global__ void flash_combine(const unsigned short* __restrict__ pO,
                              const float* __restrict__ ml,
                              unsigned short* __restrict__ acat) {
  int n = blockIdx.x, t = threadIdx.x;
  int h = t >> 5, e0 = (t & 31) * 8;
  float ms[NSPLIT], ls[NSPLIT];
  float M = -1e30f;
#pragma unroll
  for (int s = 0; s < NSPLIT; ++s) {
    size_t b = ((size_t)(s * NHEAD + h) * NTOK + n) * 2;
    ms[s] = ml[b]; ls[s] = ml[b + 1];
    M = fmaxf(M, ms[s]);
  }
  float den = 0.f;
  float num[8];
#pragma unroll
  for (int j = 0; j < 8; ++j) num[j] = 0.f;
#pragma unroll
  for (int s = 0; s < NSPLIT; ++s) {
    float ws = __expf(ms[s] - M);
    den += ws * ls[s];
    s16x8_t ov = *(const s16x8_t*)(pO + ((size_t)(s * NHEAD + h) * NTOK + n) * 256 + e0);
#pragma unroll
    for (int j = 0; j < 8; ++j) num[j] += ws * bf2f((unsigned short)ov[j]);
  }
  float rden = 1.0f / den;
  s16x8_t out;
#pragma unroll
  for (int j = 0; j < 8; ++j) out[j] = (short)f2bf(num[j] * rden);
  *(s16x8_t*)(acat + (size_t)n * 2048 + h * 256 + e0) = out;
}

// ---------------- fused tail: u1 GEMM + LN1 + fnn1 + fnn2 + LN2 ----------------
__global__ __launch_bounds__(256, 2) void tail_fused(
    const unsigned short* __restrict__ xa, const unsigned short* __restrict__ lwT,
    const unsigned short* __restrict__ f1T, const unsigned short* __restrict__ f2T,
    const float* __restrict__ x, const float* __restrict__ lb,
    const float* __restrict__ ln1g, const float* __restrict__ ln1b,
    const float* __restrict__ f1b, const float* __restrict__ f2b,
    const float* __restrict__ ln2g, const float* __restrict__ ln2b,
    float* __restrict__ out) {
  __shared__ unsigned short As[16 * 32];
  __shared__ unsigned short Bs[256 * 32];
  __shared__ unsigned short Xs[16 * 256];
  __shared__ float red[16][4][2];
  const int t = threadIdx.x, w = t >> 6, l = t & 63;
  const int l15 = l & 15, lhi = l >> 4;
  const int row0 = blockIdx.x * 16;
  const int wc = w * 64;
  const int srow = l >> 2, spc = (l & 3) * 16;

  // ---- phase 1: u1 = xa @ lwT (K=512) ----
  f32x4_t acc[4];
#pragma unroll
  for (int n = 0; n < 4; ++n) acc[n] = (f32x4_t){0.f, 0.f, 0.f, 0.f};
  for (int kt = 0; kt < 16; ++kt) {
    __syncthreads();
    if (w == 0) {
      int ar = srow;
      int lcb = spc ^ (((ar >> 1) & 3) << 4);
      gload_lds16(xa + (size_t)(row0 + ar) * 512 + kt * 32 + (lcb >> 1), &As[0]);
    }
#pragma unroll
    for (int c = w; c < 16; c += 4) {
      int br = c * 16 + srow;
      int lcb = spc ^ (((br >> 1) & 3) << 4);
      gload_lds16(lwT + (size_t)br * 512 + kt * 32 + (lcb >> 1), &Bs[c * 512]);
    }
    __syncthreads();
    bf16x8_t af = *(const bf16x8_t*)(&As[(l15 * 64 + ((lhi * 16) ^ (((l15 >> 1) & 3) << 4))) >> 1]);
#pragma unroll
    for (int n = 0; n < 4; ++n) {
      int br = wc + n * 16 + l15;
      bf16x8_t bfr = *(const bf16x8_t*)(&Bs[(br * 64 + ((lhi * 16) ^ (((br >> 1) & 3) << 4))) >> 1]);
      acc[n] = __builtin_amdgcn_mfma_f32_16x16x32_bf16(af, bfr, acc[n], 0, 0, 0);
    }
  }
  float x1v[4][4];
#pragma unroll
  for (int r = 0; r < 4; ++r) {
    int grow = row0 + lhi * 4 + r;
#pragma unroll
    for (int n = 0; n < 4; ++n) {
      int col = wc + n * 16 + l15;
      x1v[n][r] = acc[n][r] + lb[col] + x[(size_t)grow * 256 + col];
    }
  }
#pragma unroll
  for (int r = 0; r < 4; ++r) {
    float s = x1v[0][r] + x1v[1][r] + x1v[2][r] + x1v[3][r];
    float q = x1v[0][r] * x1v[0][r] + x1v[1][r] * x1v[1][r] +
              x1v[2][r] * x1v[2][r] + x1v[3][r] * x1v[3][r];
    s = red_sum16(s); q = red_sum16(q);
    if (l15 == 0) { red[lhi * 4 + r][w][0] = s; red[lhi * 4 + r][w][1] = q; }
  }
  __syncthreads();
#pragma unroll
  for (int r = 0; r < 4; ++r) {
    int row = lhi * 4 + r;
    float s = red[row][0][0] + red[row][1][0] + red[row][2][0] + red[row][3][0];
    float q = red[row][0][1] + red[row][1][1] + red[row][2][1] + red[row][3][1];
    float mu = s * (1.0f / 256.0f);
    float var = q * (1.0f / 256.0f) - mu * mu;
    float rstd = rsqrtf(var + 1e-5f);
#pragma unroll
    for (int n = 0; n < 4; ++n) {
      int col = wc + n * 16 + l15;
      float xv = (x1v[n][r] - mu) * rstd * ln1g[col] + ln1b[col];
      x1v[n][r] = xv;
      int pb = row * 512 + ((col * 2) ^ ((row & 7) << 4));
      Xs[pb >> 1] = f2bf(xv);
    }
  }

  // ---- phase 2: t = relu(x1 @ f1T + f1b) (K=256) ----
  f32x4_t acc2[4];
#pragma unroll
  for (int n = 0; n < 4; ++n) acc2[n] = (f32x4_t){0.f, 0.f, 0.f, 0.f};
  for (int kt = 0; kt < 8; ++kt) {
    __syncthreads();
#pragma unroll
    for (int c = w; c < 16; c += 4) {
      int br = c * 16 + srow;
      int lcb = spc ^ (((br >> 1) & 3) << 4);
      gload_lds16(f1T + (size_t)br * 256 + kt * 32 + (lcb >> 1), &Bs[c * 512]);
    }
    __syncthreads();
    bf16x8_t af = *(const bf16x8_t*)(&Xs[(l15 * 512 + (((kt * 32 + lhi * 8) * 2) ^ ((l15 & 7) << 4))) >> 1]);
#pragma unroll
    for (int n = 0; n < 4; ++n) {
      int br = wc + n * 16 + l15;
      bf16x8_t bfr = *(const bf16x8_t*)(&Bs[(br * 64 + ((lhi * 16) ^ (((br >> 1) & 3) << 4))) >> 1]);
      acc2[n] = __builtin_amdgcn_mfma_f32_16x16x32_bf16(af, bfr, acc2[n], 0, 0, 0);
    }
  }
  __syncthreads();
#pragma unroll
  for (int r = 0; r < 4; ++r) {
    int row = lhi * 4 + r;
#pragma unroll
    for (int n = 0; n < 4; ++n) {
      int col = wc + n * 16 + l15;
      float v = fmaxf(acc2[n][r] + f1b[col], 0.f);
      int pb = row * 512 + ((col * 2) ^ ((row & 7) << 4));
      Xs[pb >> 1] = f2bf(v);
    }
  }

  // ---- phase 3: u2 = tb @ f2T + f2b + x1 (K=256), then LN2 ----
  f32x4_t acc3[4];
#pragma unroll
  for (int n = 0; n < 4; ++n) acc3[n] = (f32x4_t){0.f, 0.f, 0.f, 0.f};
  for (int kt = 0; kt < 8; ++kt) {
    __syncthreads();
#pragma unroll
    for (int c = w; c < 16; c += 4) {
      int br = c * 16 + srow;
      int lcb = spc ^ (((br >> 1) & 3) << 4);
      gload_lds16(f2T + (size_t)br * 256 + kt * 32 + (lcb >> 1), &Bs[c * 512]);
    }
    __syncthreads();
    bf16x8_t af = *(const bf16x8_t*)(&Xs[(l15 * 512 + (((kt * 32 + lhi * 8) * 2) ^ ((l15 & 7) << 4))) >> 1]);
#pragma unroll
    for (int n = 0; n < 4; ++n) {
      int br = wc + n * 16 + l15;
      bf16x8_t bfr = *(const bf16x8_t*)(&Bs[(br * 64 + ((lhi * 16) ^ (((br >> 1) & 3) << 4))) >> 1]);
      acc3[n] = __builtin_amdgcn_mfma_f32_16x16x32_bf16(af, bfr, acc3[n], 0, 0, 0);
    }
  }
  float u2v[4][4];
#pragma unroll
  for (int r = 0; r < 4; ++r) {
#pragma unroll
    for (int n = 0; n < 4; ++n) {
      int col = wc + n * 16 + l15;
      u2v[n][r] = acc3[n][r] + f2b[col] + x1v[n][r];
    }
  }
  __syncthreads();
#pragma unroll
  for (int r = 0; r < 4; ++r) {
    float s = u2v[0][r] + u2v[1][r] + u2v[2][r] + u2v[3][r];
    float q = u2v[0][r] * u2v[0][r] + u2v[1][r] * u2v[1][r] +
              u2v[2][r] * u2v[2][r] + u2v[3][r] * u2v[3][r];
    s = red_sum16(s); q = red_sum16(q);
    if (l15 == 0) { red[lhi * 4 + r][w][0] = s; red[lhi * 4 + r][w][1] = q; }
  }
  __syncthreads();
#pragma unroll
  for (int r = 0; r < 4; ++r) {
    int row = lhi * 4 + r;
    int grow = row0 + row;
    float s = red[row][0][0] + red[row][1][0] + red[row][2][0] + red[row][3][0];
    float q = red[row][0][1] + red[row][1][1] + red[row][2][1] + red[row][3][1];
    float mu = s * (1.0f / 256.0f);
    float var = q * (1.0f / 256.0f) - mu * mu;
    float rstd = rsqrtf(var + 1e-5f);
#pragma unroll
    for (int n = 0; n < 4; ++n) {
      int col = wc + n * 16 + l15;
      out[(size_t)grow * 256 + col] = (u2v[n][r] - mu) * rstd * ln2g[col] + ln2b[col];
    }
  }
}

// ---------------- launcher ----------------
extern "C" void kernel_launch(void* const* d_in, const int* in_sizes, int n_in,
                              void* d_out, int out_size, void* d_ws, size_t ws_size,
                              hipStream_t stream) {
  const float* x    = (const float*)d_in[0];
  const float* deg  = (const float*)d_in[1];
  const float* WQ   = (const float*)d_in[2];
  const float* WK   = (const float*)d_in[3];
  const float* WV   = (const float*)d_in[4];
  const float* law  = (const float*)d_in[5];
  const float* lab  = (const float*)d_in[6];
  const float* lw   = (const float*)d_in[7];
  const float* lb   = (const float*)d_in[8];
  const float* ln1g = (const float*)d_in[9];
  const float* ln1b = (const float*)d_in[10];
  const float* f1w  = (const float*)d_in[11];
  const float* f1b  = (const float*)d_in[12];
  const float* f2w  = (const float*)d_in[13];
  const float* f2b  = (const float*)d_in[14];
  const float* ln2g = (const float*)d_in[15];
  const float* ln2b = (const float*)d_in[16];

  char* ws = (char*)d_ws;
  size_t off = 0;
  auto alloc = [&](size_t bytes) {
    void* p = ws + off;
    off += (bytes + 255) & ~(size_t)255;
    return p;
  };
  unsigned short* qkvwT = (unsigned short*)alloc((size_t)6144 * 256 * 2);
  unsigned short* lawT  = (unsigned short*)alloc((size_t)256 * 2048 * 2);
  unsigned short* lwT   = (unsigned short*)alloc((size_t)256 * 512 * 2);
  unsigned short* f1T   = (unsigned short*)alloc((size_t)256 * 256 * 2);
  unsigned short* f2T   = (unsigned short*)alloc((size_t)256 * 256 * 2);
  unsigned short* xa    = (unsigned short*)alloc((size_t)NTOK * 512 * 2);
  unsigned short* qkv   = (unsigned short*)alloc((size_t)NTOK * 6144 * 2);
  unsigned short* acat  = (unsigned short*)alloc((size_t)NTOK * 2048 * 2);
  unsigned short* pO    = (unsigned short*)alloc((size_t)NSPLIT * NHEAD * NTOK * 256 * 2);
  float*          mlp   = (float*)alloc((size_t)NSPLIT * NHEAD * NTOK * 2 * 4);
  float*          apart = (float*)alloc((size_t)4 * NTOK * 256 * 4);

  prep_all<<<624, 256, 0, stream>>>(WQ, WK, WV, law, lw, f1w, f2w, x,
                                    qkvwT, lawT, lwT, f1T, f2T, xa);

  // QKV: (3072x256)@(256x6144) -> qkv bf16
  gemm_kernel<128, 128><<<dim3(48, 24), 256, 0, stream>>>(
      xa, 512, qkvwT, 256, qkv, 6144, 256, nullptr, nullptr, 0, nullptr, 2, nullptr, 0);

  flash_kernel<<<NTOK / 64 * NHEAD * NSPLIT, 256, 0, stream>>>(qkv, pO, mlp);
  flash_combine<<<NTOK, 256, 0, stream>>>(pO, mlp, acat);

  // attn_out split-K x4 -> f32 partials, then reduce (+bias)*rsqrt(deg) -> xa[:,256:512]
  gemm_kernel<64, 64><<<dim3(4, 48, 4), 256, 0, stream>>>(
      acat, 2048, lawT, 2048, nullptr, 256, 512, nullptr, nullptr, 0, nullptr, 8,
      apart, (long)NTOK * 256);
  attn_reduce<<<NTOK, 256, 0, stream>>>(apart, lab, deg, xa);

  // fused tail: u1 -> LN1 -> fnn1 -> fnn2 -> LN2 -> out
  tail_fused<<<NTOK / 16, 256, 0, stream>>>(
      xa, lwT, f1T, f2T, x, lb, ln1g, ln1b, f1b, f2b, ln2g, ln2b, (float*)d_out);
}